// Round 5
// baseline (364.606 us; speedup 1.0000x reference)
//
#include <hip/hip_runtime.h>
#include <hip/hip_bf16.h>

#define B_ 8
#define S_ 2048
#define E_ 1024

using f32x4 = __attribute__((ext_vector_type(4))) float;
using s16x8 = __attribute__((ext_vector_type(8))) short;
using u16x8 = __attribute__((ext_vector_type(8))) unsigned short;

typedef __attribute__((address_space(1))) unsigned int glb_u32;
typedef __attribute__((address_space(3))) unsigned int lds_u32;

#define FENCE() __builtin_amdgcn_sched_barrier(0)

static __device__ __forceinline__ unsigned short f2bf(float f) {
    union { float f; unsigned int u; } v; v.f = f;
    unsigned int u = v.u;
    u += 0x7FFFu + ((u >> 16) & 1u);   // round-to-nearest-even
    return (unsigned short)(u >> 16);
}
static __device__ __forceinline__ float bf2f(unsigned short h) {
    union { unsigned int u; float f; } v; v.u = ((unsigned int)h) << 16;
    return v.f;
}

// ---------------------------------------------------------------------------
// Mask canonicalizer: jax bool mask may arrive as uint8, int32 or float32.
// ---------------------------------------------------------------------------
__global__ __launch_bounds__(256) void mask_canon_kernel(
    const unsigned char* __restrict__ src, unsigned char* __restrict__ dst, int n)
{
    __shared__ int flags;
    if (threadIdx.x == 0) flags = 0;
    __syncthreads();
    int f = 0;
    for (int j = threadIdx.x; j < n; j += 256) {
        unsigned char b = src[j];
        if (b) {
            int p = j & 3;
            if (p == 1) f |= 1;
            if (p >= 2) f |= 2;
        }
    }
    if (f) atomicOr(&flags, f);
    __syncthreads();
    const int fl = flags;
    for (int i = threadIdx.x; i < n; i += 256) {
        unsigned char v;
        if (fl & 1)      v = (unsigned char)(src[i] != 0);
        else if (fl & 2) v = (unsigned char)(((const float*)(const void*)src)[i] != 0.0f);
        else             v = (unsigned char)(((const int*)(const void*)src)[i] != 0);
        dst[i] = v;
    }
}

// ---------------------------------------------------------------------------
// fp32 -> bf16 bulk convert.
// ---------------------------------------------------------------------------
__global__ __launch_bounds__(256) void cvt_bf16_kernel(
    const float* __restrict__ src, unsigned short* __restrict__ dst, int n8)
{
    const int stride = gridDim.x * 256;
    for (int i = blockIdx.x * 256 + threadIdx.x; i < n8; i += stride) {
        float4 a = *(const float4*)(src + (size_t)i * 8);
        float4 b = *(const float4*)(src + (size_t)i * 8 + 4);
        u16x8 o;
        o[0]=f2bf(a.x); o[1]=f2bf(a.y); o[2]=f2bf(a.z); o[3]=f2bf(a.w);
        o[4]=f2bf(b.x); o[5]=f2bf(b.y); o[6]=f2bf(b.z); o[7]=f2bf(b.w);
        *(u16x8*)(dst + (size_t)i * 8) = o;
    }
}

// ---------------------------------------------------------------------------
// 256x256 8-phase bf16 NT GEMM (m201 template, plain HIP).
//  - 8 waves (2M x 4N); BK=64; LDS 128KB double-buffered; st_16x32 swizzle
//    via pre-swizzled global SOURCE + swizzled read (0 bank conflicts, R4).
//  - All 24 frag reads issued in ph1 ordered (af03,bf01,af47,bf23); full
//    lgkmcnt(0) drain AFTER ph1's MFMA cluster but BEFORE ph1-end barrier
//    (race ledger identical to R4: no buffer overwrite issues until every
//    wave's reads completed).
//  - sched_barrier(0) fences box each MFMA cluster into its phase (rule #18:
//    without them hipcc hoists register-only MFMA across barriers/waitcnts,
//    collapsing the pipeline -> R4's 32% MfmaUtil).
//  - vmcnt(6) once per K-tile: exactly tile t+2's {A0,A1,B0} stay in flight.
// EPI: 0=QK(scale+mask->bf16) 1=PV(f32) 2=bias[ncol]->bf16 3=bias[mrow]->bf16
// ---------------------------------------------------------------------------
template<int EPI>
__global__ __launch_bounds__(512, 2) void gemm256(
    const unsigned short* __restrict__ A, const unsigned short* __restrict__ B,
    void* __restrict__ Cout,
    long long sAz, long long sBz, long long sCz,
    int lda, int ldb, int ldc, int K,
    const unsigned char* __restrict__ mask, int maskStride, float scale,
    const float* __restrict__ bias)
{
    __shared__ unsigned short lds[65536];   // 128 KB
    const int tid = threadIdx.x;
    const int lane = tid & 63, w = tid >> 6;
    const int wr = w >> 2, wc = w & 3;          // 2 x 4 waves
    const int fr = lane & 15, ch = lane >> 4;

    // T1: XCD-aware chunked swizzle of flattened block id (nwg % 8 == 0)
    const int gx = gridDim.x, gy = gridDim.y;
    const int nwg = gx * gy * gridDim.z;
    int bid = blockIdx.x + gx * (blockIdx.y + gy * blockIdx.z);
    bid = (bid & 7) * (nwg >> 3) + (bid >> 3);
    const int bx = bid % gx; int tmp = bid / gx;
    const int by = tmp % gy; const int bz = tmp / gy;

    const unsigned short* Ab = A + (size_t)bz * sAz;
    const unsigned short* Bb = B + (size_t)bz * sBz;
    const int m0 = by * 256, n0 = bx * 256;

    // swizzled frag-read lane offset (ushort units)
    const int rdlane = fr * 32 + ((ch * 8) ^ ((fr & 8) ? 16 : 0));
    // stage source mapping (inverse swizzle of the linear lane->phys write)
    const int local = (lane * 16) ^ (lane & 32);
    const int rloc = local >> 6;          // row within 16-row chunk
    const int cloc = (local >> 4) & 3;    // 16B col chunk

    f32x4 acc[8][4] = {};
    const int NT = K >> 6;

    auto STAGE = [&](const unsigned short* __restrict__ src, int ld, int base,
                     int ts, int half, int matoff, unsigned bo) {
        const int k0 = ts * 64;
        const int rowb = half * 128 + w * 16;
        #pragma unroll
        for (int kk = 0; kk < 2; ++kk) {
            const unsigned short* g = src + (size_t)(base + rowb + rloc) * ld
                                          + (k0 + kk * 32 + cloc * 8);
            __builtin_amdgcn_global_load_lds((const glb_u32*)g,
                (lds_u32*)&lds[bo + matoff + kk * 8192 + rowb * 32], 16, 0, 0);
        }
    };

    // prologue: tile0 fully + tile1 {A0,A1,B0}
    STAGE(Ab, lda, m0, 0, 0, 0, 0);      STAGE(Ab, lda, m0, 0, 1, 0, 0);
    STAGE(Bb, ldb, n0, 0, 0, 16384, 0);  STAGE(Bb, ldb, n0, 0, 1, 16384, 0);
    STAGE(Ab, lda, m0, 1, 0, 0, 32768);  STAGE(Ab, lda, m0, 1, 1, 0, 32768);
    STAGE(Bb, ldb, n0, 1, 0, 16384, 32768);
    asm volatile("s_waitcnt vmcnt(6)" ::: "memory");
    __builtin_amdgcn_s_barrier();

    for (int t = 0; t < NT; ++t) {
        const unsigned bo = (unsigned)(t & 1) * 32768u;
        const unsigned nbo = bo ^ 32768u;
        const int tp1 = (t + 1 < NT) ? t + 1 : NT - 1;
        const int tp2 = (t + 2 < NT) ? t + 2 : NT - 1;

        s16x8 af[8][2], bfv[4][2];
        // ---- phase 1: reads ordered {af03, bf01, af47, bf23} + stage B1(t+1)
        #pragma unroll
        for (int i = 0; i < 4; ++i)
            #pragma unroll
            for (int kk = 0; kk < 2; ++kk)
                af[i][kk] = *(const s16x8*)&lds[bo + kk * 8192 + (wr * 128 + i * 16) * 32 + rdlane];
        #pragma unroll
        for (int j = 0; j < 2; ++j)
            #pragma unroll
            for (int kk = 0; kk < 2; ++kk)
                bfv[j][kk] = *(const s16x8*)&lds[bo + 16384 + kk * 8192 + (wc * 64 + j * 16) * 32 + rdlane];
        #pragma unroll
        for (int i = 4; i < 8; ++i)
            #pragma unroll
            for (int kk = 0; kk < 2; ++kk)
                af[i][kk] = *(const s16x8*)&lds[bo + kk * 8192 + (wr * 128 + i * 16) * 32 + rdlane];
        #pragma unroll
        for (int j = 2; j < 4; ++j)
            #pragma unroll
            for (int kk = 0; kk < 2; ++kk)
                bfv[j][kk] = *(const s16x8*)&lds[bo + 16384 + kk * 8192 + (wc * 64 + j * 16) * 32 + rdlane];
        STAGE(Bb, ldb, n0, tp1, 1, 16384, nbo);
        __builtin_amdgcn_s_barrier();
        FENCE();
        __builtin_amdgcn_s_setprio(1);
        #pragma unroll
        for (int i = 0; i < 4; ++i)
            #pragma unroll
            for (int j = 0; j < 2; ++j)
                #pragma unroll
                for (int kk = 0; kk < 2; ++kk)
                    acc[i][j] = __builtin_amdgcn_mfma_f32_16x16x32_bf16(af[i][kk], bfv[j][kk], acc[i][j], 0, 0, 0);
        __builtin_amdgcn_s_setprio(0);
        FENCE();
        asm volatile("s_waitcnt lgkmcnt(0)" ::: "memory");   // race ledger: all 24 reads done
        FENCE();
        __builtin_amdgcn_s_barrier();
        // ---- phase 2: stage A0(t+2) into current buf; MFMA Q01 ----
        STAGE(Ab, lda, m0, tp2, 0, 0, bo);
        __builtin_amdgcn_s_barrier();
        FENCE();
        __builtin_amdgcn_s_setprio(1);
        #pragma unroll
        for (int i = 0; i < 4; ++i)
            #pragma unroll
            for (int j = 0; j < 2; ++j)
                #pragma unroll
                for (int kk = 0; kk < 2; ++kk)
                    acc[i][2 + j] = __builtin_amdgcn_mfma_f32_16x16x32_bf16(af[i][kk], bfv[2 + j][kk], acc[i][2 + j], 0, 0, 0);
        __builtin_amdgcn_s_setprio(0);
        FENCE();
        __builtin_amdgcn_s_barrier();
        // ---- phase 3: stage A1(t+2); MFMA Q10 ----
        STAGE(Ab, lda, m0, tp2, 1, 0, bo);
        __builtin_amdgcn_s_barrier();
        FENCE();
        __builtin_amdgcn_s_setprio(1);
        #pragma unroll
        for (int i = 0; i < 4; ++i)
            #pragma unroll
            for (int j = 0; j < 2; ++j)
                #pragma unroll
                for (int kk = 0; kk < 2; ++kk)
                    acc[4 + i][j] = __builtin_amdgcn_mfma_f32_16x16x32_bf16(af[4 + i][kk], bfv[j][kk], acc[4 + i][j], 0, 0, 0);
        __builtin_amdgcn_s_setprio(0);
        FENCE();
        __builtin_amdgcn_s_barrier();
        // ---- phase 4: stage B0(t+2); MFMA Q11; counted vmcnt ----
        STAGE(Bb, ldb, n0, tp2, 0, 16384, bo);
        __builtin_amdgcn_s_barrier();
        FENCE();
        __builtin_amdgcn_s_setprio(1);
        #pragma unroll
        for (int i = 0; i < 4; ++i)
            #pragma unroll
            for (int j = 0; j < 2; ++j)
                #pragma unroll
                for (int kk = 0; kk < 2; ++kk)
                    acc[4 + i][2 + j] = __builtin_amdgcn_mfma_f32_16x16x32_bf16(af[4 + i][kk], bfv[2 + j][kk], acc[4 + i][2 + j], 0, 0, 0);
        __builtin_amdgcn_s_setprio(0);
        FENCE();
        asm volatile("s_waitcnt vmcnt(6)" ::: "memory");
        FENCE();
        __builtin_amdgcn_s_barrier();
    }

    // ---------------- epilogue ----------------
    if constexpr (EPI == 1) {
        float* Cb = (float*)Cout + (size_t)bz * sCz;
        #pragma unroll
        for (int j = 0; j < 4; ++j) {
            const int ncol = n0 + wc * 64 + j * 16 + fr;
            #pragma unroll
            for (int i = 0; i < 8; ++i)
                #pragma unroll
                for (int r = 0; r < 4; ++r) {
                    const int mrow = m0 + wr * 128 + i * 16 + ch * 4 + r;
                    Cb[(size_t)mrow * ldc + ncol] = acc[i][j][r];
                }
        }
    } else {
        unsigned short* Cb = (unsigned short*)Cout + (size_t)bz * sCz;
        const unsigned char* mb = (EPI == 0) ? mask + (size_t)bz * maskStride : nullptr;
        #pragma unroll
        for (int j = 0; j < 4; ++j) {
            const int ncol = n0 + wc * 64 + j * 16 + fr;
            bool msk = false; float bn = 0.f;
            if constexpr (EPI == 0) msk = mb[ncol] != 0;
            if constexpr (EPI == 2) bn = bias[ncol];
            #pragma unroll
            for (int i = 0; i < 8; ++i) {
                #pragma unroll
                for (int r = 0; r < 4; ++r) {
                    const int mrow = m0 + wr * 128 + i * 16 + ch * 4 + r;
                    float val;
                    if constexpr (EPI == 0)      val = msk ? 1e-9f : acc[i][j][r] * scale;
                    else if constexpr (EPI == 2) val = acc[i][j][r] + bn;
                    else                         val = acc[i][j][r] + bias[mrow];
                    Cb[(size_t)mrow * ldc + ncol] = f2bf(val);
                }
            }
        }
    }
}

// ---------------------------------------------------------------------------
// Row softmax over S_=2048 bf16 scores, in place.
// ---------------------------------------------------------------------------
__global__ __launch_bounds__(256) void softmax_kernel(unsigned short* __restrict__ P)
{
    const int row = blockIdx.x;
    const int tid = threadIdx.x;
    unsigned short* prow = P + (size_t)row * S_;
    u16x8 v = *(const u16x8*)&prow[tid * 8];
    float f[8];
    #pragma unroll
    for (int j = 0; j < 8; ++j) f[j] = bf2f(v[j]);
    float m = f[0];
    #pragma unroll
    for (int j = 1; j < 8; ++j) m = fmaxf(m, f[j]);
    #pragma unroll
    for (int o = 1; o < 64; o <<= 1) m = fmaxf(m, __shfl_xor(m, o, 64));
    __shared__ float smax[4], ssum[4];
    const int w = tid >> 6, lane = tid & 63;
    if (lane == 0) smax[w] = m;
    __syncthreads();
    m = fmaxf(fmaxf(smax[0], smax[1]), fmaxf(smax[2], smax[3]));
    float e[8], s = 0.f;
    #pragma unroll
    for (int j = 0; j < 8; ++j) { e[j] = expf(f[j] - m); s += e[j]; }
    #pragma unroll
    for (int o = 1; o < 64; o <<= 1) s += __shfl_xor(s, o, 64);
    if (lane == 0) ssum[w] = s;
    __syncthreads();
    s = ssum[0] + ssum[1] + ssum[2] + ssum[3];
    const float inv = 1.0f / s;
    u16x8 o8;
    #pragma unroll
    for (int j = 0; j < 8; ++j) o8[j] = f2bf(e[j] * inv);
    *(u16x8*)&prow[tid * 8] = o8;
}

// ---------------------------------------------------------------------------
extern "C" void kernel_launch(void* const* d_in, const int* in_sizes, int n_in,
                              void* d_out, int out_size, void* d_ws, size_t ws_size,
                              hipStream_t stream)
{
    const float* x  = (const float*)d_in[0];
    const float* Wq = (const float*)d_in[1];
    const float* bq = (const float*)d_in[2];
    const float* Wk = (const float*)d_in[3];
    const float* bk = (const float*)d_in[4];
    const float* Wv = (const float*)d_in[5];
    const float* bv = (const float*)d_in[6];
    const unsigned char* mraw = (const unsigned char*)d_in[7];

    const int BS = B_ * S_;                      // 16384
    unsigned short* Qb = (unsigned short*)d_ws;
    unsigned short* Kb = Qb + (size_t)BS * E_;
    unsigned short* VT = Kb + (size_t)BS * E_;
    unsigned short* Sc = VT + (size_t)BS * E_;
    unsigned short* xb = Sc;                                    // aliases Sc
    unsigned short* Wqb = Sc + (size_t)BS * E_;
    unsigned short* Wkb = Wqb + (size_t)E_ * E_;
    unsigned short* Wvb = Wkb + (size_t)E_ * E_;
    unsigned char* mcanon = (unsigned char*)(Sc + (size_t)B_ * S_ * S_);

    mask_canon_kernel<<<1, 256, 0, stream>>>(mraw, mcanon, BS);

    cvt_bf16_kernel<<<2048, 256, 0, stream>>>(x, xb, BS * E_ / 8);
    cvt_bf16_kernel<<<512, 256, 0, stream>>>(Wq, Wqb, E_ * E_ / 8);
    cvt_bf16_kernel<<<512, 256, 0, stream>>>(Wk, Wkb, E_ * E_ / 8);
    cvt_bf16_kernel<<<512, 256, 0, stream>>>(Wv, Wvb, E_ * E_ / 8);

    // Q = xb @ Wq^T + bq ; K = xb @ Wk^T + bk   (bf16 [BS][E])
    gemm256<2><<<dim3(E_ / 256, BS / 256), 512, 0, stream>>>(
        xb, Wqb, (void*)Qb, 0, 0, 0, E_, E_, E_, E_, nullptr, 0, 1.0f, bq);
    gemm256<2><<<dim3(E_ / 256, BS / 256), 512, 0, stream>>>(
        xb, Wkb, (void*)Kb, 0, 0, 0, E_, E_, E_, E_, nullptr, 0, 1.0f, bk);
    // VT[e][bs] = Wv[e,:] . x[bs,:] + bv[e]
    gemm256<3><<<dim3(BS / 256, E_ / 256), 512, 0, stream>>>(
        Wvb, xb, (void*)VT, 0, 0, 0, E_, E_, BS, E_, nullptr, 0, 1.0f, bv);

    // scores = (Q.K^T)/32, mask fill 1e-9, bf16
    gemm256<0><<<dim3(S_ / 256, S_ / 256, B_), 512, 0, stream>>>(
        Qb, Kb, (void*)Sc,
        (long long)S_ * E_, (long long)S_ * E_, (long long)S_ * S_,
        E_, E_, S_, E_, mcanon, S_, 0.03125f, nullptr);

    softmax_kernel<<<dim3(BS), 256, 0, stream>>>(Sc);

    // out = P . V (via V^T, NT)
    gemm256<1><<<dim3(E_ / 256, S_ / 256, B_), 512, 0, stream>>>(
        Sc, VT, d_out,
        (long long)S_ * S_, (long long)S_, (long long)S_ * E_,
        S_, BS, E_, S_, nullptr, 0, 1.0f, nullptr);
}

// Round 6
// 360.425 us; speedup vs baseline: 1.0116x; 1.0116x over previous
//
#include <hip/hip_runtime.h>
#include <hip/hip_bf16.h>

#define B_ 8
#define S_ 2048
#define E_ 1024

using f32x4 = __attribute__((ext_vector_type(4))) float;
using s16x8 = __attribute__((ext_vector_type(8))) short;
using u16x8 = __attribute__((ext_vector_type(8))) unsigned short;

typedef __attribute__((address_space(1))) unsigned int glb_u32;
typedef __attribute__((address_space(3))) unsigned int lds_u32;

#define FENCE() __builtin_amdgcn_sched_barrier(0)

static __device__ __forceinline__ unsigned short f2bf(float f) {
    union { float f; unsigned int u; } v; v.f = f;
    unsigned int u = v.u;
    u += 0x7FFFu + ((u >> 16) & 1u);   // round-to-nearest-even
    return (unsigned short)(u >> 16);
}
static __device__ __forceinline__ float bf2f(unsigned short h) {
    union { unsigned int u; float f; } v; v.u = ((unsigned int)h) << 16;
    return v.f;
}

// ---------------------------------------------------------------------------
// Mask canonicalizer: jax bool mask may arrive as uint8, int32 or float32.
// ---------------------------------------------------------------------------
__global__ __launch_bounds__(256) void mask_canon_kernel(
    const unsigned char* __restrict__ src, unsigned char* __restrict__ dst, int n)
{
    __shared__ int flags;
    if (threadIdx.x == 0) flags = 0;
    __syncthreads();
    int f = 0;
    for (int j = threadIdx.x; j < n; j += 256) {
        unsigned char b = src[j];
        if (b) {
            int p = j & 3;
            if (p == 1) f |= 1;
            if (p >= 2) f |= 2;
        }
    }
    if (f) atomicOr(&flags, f);
    __syncthreads();
    const int fl = flags;
    for (int i = threadIdx.x; i < n; i += 256) {
        unsigned char v;
        if (fl & 1)      v = (unsigned char)(src[i] != 0);
        else if (fl & 2) v = (unsigned char)(((const float*)(const void*)src)[i] != 0.0f);
        else             v = (unsigned char)(((const int*)(const void*)src)[i] != 0);
        dst[i] = v;
    }
}

// ---------------------------------------------------------------------------
// fp32 -> bf16 bulk convert.
// ---------------------------------------------------------------------------
__global__ __launch_bounds__(256) void cvt_bf16_kernel(
    const float* __restrict__ src, unsigned short* __restrict__ dst, int n8)
{
    const int stride = gridDim.x * 256;
    for (int i = blockIdx.x * 256 + threadIdx.x; i < n8; i += stride) {
        float4 a = *(const float4*)(src + (size_t)i * 8);
        float4 b = *(const float4*)(src + (size_t)i * 8 + 4);
        u16x8 o;
        o[0]=f2bf(a.x); o[1]=f2bf(a.y); o[2]=f2bf(a.z); o[3]=f2bf(a.w);
        o[4]=f2bf(b.x); o[5]=f2bf(b.y); o[6]=f2bf(b.z); o[7]=f2bf(b.w);
        *(u16x8*)(dst + (size_t)i * 8) = o;
    }
}

// ---------------------------------------------------------------------------
// 256x256 8-phase bf16 NT GEMM — m201 template with per-phase read spread.
//  - 8 waves (2M x 4N); BK=64; LDS 128KB double-buffered; st_16x32 swizzle
//    via pre-swizzled global SOURCE + swizzled read (0 bank conflicts, R4).
//  - Per-phase ds_reads (12/4/8/0) so LDS service overlaps MFMA across
//    phases via wave stagger (R4/R5's all-in-ph1 burst serialized them).
//  - Race ledger: B reads of current buf complete before ph2-exit barrier
//    (lgkm0 in ph1+ph2); A reads complete before ph3-exit. B0(t+2) staged
//    ph3 (after ph2-exit), A0/A1(t+2) staged ph4 (after ph3-exit).
//  - vmcnt(6) at end of ph4 only: retains exactly this iter's 6 t+2 issues,
//    forcing B1(t+1) + all older stages complete before next iter's reads.
// EPI: 0=QK(scale+mask->bf16) 1=PV(f32) 2=bias[ncol]->bf16 3=bias[mrow]->bf16
// ---------------------------------------------------------------------------
template<int EPI>
__global__ __launch_bounds__(512, 2) void gemm256(
    const unsigned short* __restrict__ A, const unsigned short* __restrict__ B,
    void* __restrict__ Cout,
    long long sAz, long long sBz, long long sCz,
    int lda, int ldb, int ldc, int K,
    const unsigned char* __restrict__ mask, int maskStride, float scale,
    const float* __restrict__ bias)
{
    __shared__ unsigned short lds[65536];   // 128 KB
    const int tid = threadIdx.x;
    const int lane = tid & 63, w = tid >> 6;
    const int wr = w >> 2, wc = w & 3;          // 2 x 4 waves
    const int fr = lane & 15, ch = lane >> 4;

    // T1: XCD-aware chunked swizzle of flattened block id (nwg % 8 == 0)
    const int gx = gridDim.x, gy = gridDim.y;
    const int nwg = gx * gy * gridDim.z;
    int bid = blockIdx.x + gx * (blockIdx.y + gy * blockIdx.z);
    bid = (bid & 7) * (nwg >> 3) + (bid >> 3);
    const int bx = bid % gx; int tmp = bid / gx;
    const int by = tmp % gy; const int bz = tmp / gy;

    const unsigned short* Ab = A + (size_t)bz * sAz;
    const unsigned short* Bb = B + (size_t)bz * sBz;
    const int m0 = by * 256, n0 = bx * 256;

    // swizzled frag-read lane offset (ushort units)
    const int rdlane = fr * 32 + ((ch * 8) ^ ((fr & 8) ? 16 : 0));
    // stage source mapping (inverse swizzle of the linear lane->phys write)
    const int local = (lane * 16) ^ (lane & 32);
    const int rloc = local >> 6;          // row within 16-row chunk
    const int cloc = (local >> 4) & 3;    // 16B col chunk

    f32x4 acc[8][4] = {};
    const int NT = K >> 6;

    auto STAGE = [&](const unsigned short* __restrict__ src, int ld, int base,
                     int ts, int half, int matoff, unsigned bo) {
        const int k0 = ts * 64;
        const int rowb = half * 128 + w * 16;
        #pragma unroll
        for (int kk = 0; kk < 2; ++kk) {
            const unsigned short* g = src + (size_t)(base + rowb + rloc) * ld
                                          + (k0 + kk * 32 + cloc * 8);
            __builtin_amdgcn_global_load_lds((const glb_u32*)g,
                (lds_u32*)&lds[bo + matoff + kk * 8192 + rowb * 32], 16, 0, 0);
        }
    };

    // prologue: tile0 fully + tile1 {A0,A1,B0}
    STAGE(Ab, lda, m0, 0, 0, 0, 0);      STAGE(Ab, lda, m0, 0, 1, 0, 0);
    STAGE(Bb, ldb, n0, 0, 0, 16384, 0);  STAGE(Bb, ldb, n0, 0, 1, 16384, 0);
    STAGE(Ab, lda, m0, 1, 0, 0, 32768);  STAGE(Ab, lda, m0, 1, 1, 0, 32768);
    STAGE(Bb, ldb, n0, 1, 0, 16384, 32768);
    asm volatile("s_waitcnt vmcnt(6)" ::: "memory");
    __builtin_amdgcn_s_barrier();

    for (int t = 0; t < NT; ++t) {
        const unsigned bo = (unsigned)(t & 1) * 32768u;
        const unsigned nbo = bo ^ 32768u;
        const int tp1 = (t + 1 < NT) ? t + 1 : NT - 1;
        const int tp2 = (t + 2 < NT) ? t + 2 : NT - 1;

        s16x8 af[8][2], bfv[4][2];
        // ===== phase 1: read af[0:4]+bf[0:2] (12); stage B1(t+1)->nbo =====
        #pragma unroll
        for (int i = 0; i < 4; ++i)
            #pragma unroll
            for (int kk = 0; kk < 2; ++kk)
                af[i][kk] = *(const s16x8*)&lds[bo + kk * 8192 + (wr * 128 + i * 16) * 32 + rdlane];
        #pragma unroll
        for (int j = 0; j < 2; ++j)
            #pragma unroll
            for (int kk = 0; kk < 2; ++kk)
                bfv[j][kk] = *(const s16x8*)&lds[bo + 16384 + kk * 8192 + (wc * 64 + j * 16) * 32 + rdlane];
        STAGE(Bb, ldb, n0, tp1, 1, 16384, nbo);
        asm volatile("s_waitcnt lgkmcnt(8)" ::: "memory");   // pace the queue
        __builtin_amdgcn_s_barrier();
        asm volatile("s_waitcnt lgkmcnt(0)" ::: "memory");
        FENCE();
        __builtin_amdgcn_s_setprio(1);
        #pragma unroll
        for (int i = 0; i < 4; ++i)
            #pragma unroll
            for (int j = 0; j < 2; ++j)
                #pragma unroll
                for (int kk = 0; kk < 2; ++kk)
                    acc[i][j] = __builtin_amdgcn_mfma_f32_16x16x32_bf16(af[i][kk], bfv[j][kk], acc[i][j], 0, 0, 0);
        __builtin_amdgcn_s_setprio(0);
        FENCE();
        __builtin_amdgcn_s_barrier();
        // ===== phase 2: read bf[2:4] (4) =====
        #pragma unroll
        for (int j = 2; j < 4; ++j)
            #pragma unroll
            for (int kk = 0; kk < 2; ++kk)
                bfv[j][kk] = *(const s16x8*)&lds[bo + 16384 + kk * 8192 + (wc * 64 + j * 16) * 32 + rdlane];
        __builtin_amdgcn_s_barrier();
        asm volatile("s_waitcnt lgkmcnt(0)" ::: "memory");
        FENCE();
        __builtin_amdgcn_s_setprio(1);
        #pragma unroll
        for (int i = 0; i < 4; ++i)
            #pragma unroll
            for (int j = 0; j < 2; ++j)
                #pragma unroll
                for (int kk = 0; kk < 2; ++kk)
                    acc[i][2 + j] = __builtin_amdgcn_mfma_f32_16x16x32_bf16(af[i][kk], bfv[2 + j][kk], acc[i][2 + j], 0, 0, 0);
        __builtin_amdgcn_s_setprio(0);
        FENCE();
        __builtin_amdgcn_s_barrier();
        // ===== phase 3: read af[4:8] (8); stage B0(t+2)->bo =====
        #pragma unroll
        for (int i = 4; i < 8; ++i)
            #pragma unroll
            for (int kk = 0; kk < 2; ++kk)
                af[i][kk] = *(const s16x8*)&lds[bo + kk * 8192 + (wr * 128 + i * 16) * 32 + rdlane];
        STAGE(Bb, ldb, n0, tp2, 0, 16384, bo);
        __builtin_amdgcn_s_barrier();
        asm volatile("s_waitcnt lgkmcnt(0)" ::: "memory");
        FENCE();
        __builtin_amdgcn_s_setprio(1);
        #pragma unroll
        for (int i = 0; i < 4; ++i)
            #pragma unroll
            for (int j = 0; j < 2; ++j)
                #pragma unroll
                for (int kk = 0; kk < 2; ++kk)
                    acc[4 + i][j] = __builtin_amdgcn_mfma_f32_16x16x32_bf16(af[4 + i][kk], bfv[j][kk], acc[4 + i][j], 0, 0, 0);
        __builtin_amdgcn_s_setprio(0);
        FENCE();
        __builtin_amdgcn_s_barrier();
        // ===== phase 4: stage A0(t+2)+A1(t+2)->bo; counted vmcnt =====
        STAGE(Ab, lda, m0, tp2, 0, 0, bo);
        STAGE(Ab, lda, m0, tp2, 1, 0, bo);
        __builtin_amdgcn_s_barrier();
        FENCE();
        __builtin_amdgcn_s_setprio(1);
        #pragma unroll
        for (int i = 0; i < 4; ++i)
            #pragma unroll
            for (int j = 0; j < 2; ++j)
                #pragma unroll
                for (int kk = 0; kk < 2; ++kk)
                    acc[4 + i][2 + j] = __builtin_amdgcn_mfma_f32_16x16x32_bf16(af[4 + i][kk], bfv[2 + j][kk], acc[4 + i][2 + j], 0, 0, 0);
        __builtin_amdgcn_s_setprio(0);
        FENCE();
        asm volatile("s_waitcnt vmcnt(6)" ::: "memory");
        FENCE();
        __builtin_amdgcn_s_barrier();
    }

    // ---------------- epilogue ----------------
    if constexpr (EPI == 1) {
        float* Cb = (float*)Cout + (size_t)bz * sCz;
        #pragma unroll
        for (int j = 0; j < 4; ++j) {
            const int ncol = n0 + wc * 64 + j * 16 + fr;
            #pragma unroll
            for (int i = 0; i < 8; ++i)
                #pragma unroll
                for (int r = 0; r < 4; ++r) {
                    const int mrow = m0 + wr * 128 + i * 16 + ch * 4 + r;
                    Cb[(size_t)mrow * ldc + ncol] = acc[i][j][r];
                }
        }
    } else {
        unsigned short* Cb = (unsigned short*)Cout + (size_t)bz * sCz;
        const unsigned char* mb = (EPI == 0) ? mask + (size_t)bz * maskStride : nullptr;
        #pragma unroll
        for (int j = 0; j < 4; ++j) {
            const int ncol = n0 + wc * 64 + j * 16 + fr;
            bool msk = false; float bn = 0.f;
            if constexpr (EPI == 0) msk = mb[ncol] != 0;
            if constexpr (EPI == 2) bn = bias[ncol];
            #pragma unroll
            for (int i = 0; i < 8; ++i) {
                #pragma unroll
                for (int r = 0; r < 4; ++r) {
                    const int mrow = m0 + wr * 128 + i * 16 + ch * 4 + r;
                    float val;
                    if constexpr (EPI == 0)      val = msk ? 1e-9f : acc[i][j][r] * scale;
                    else if constexpr (EPI == 2) val = acc[i][j][r] + bn;
                    else                         val = acc[i][j][r] + bias[mrow];
                    Cb[(size_t)mrow * ldc + ncol] = f2bf(val);
                }
            }
        }
    }
}

// ---------------------------------------------------------------------------
// Row softmax over S_=2048 bf16 scores, in place.
// ---------------------------------------------------------------------------
__global__ __launch_bounds__(256) void softmax_kernel(unsigned short* __restrict__ P)
{
    const int row = blockIdx.x;
    const int tid = threadIdx.x;
    unsigned short* prow = P + (size_t)row * S_;
    u16x8 v = *(const u16x8*)&prow[tid * 8];
    float f[8];
    #pragma unroll
    for (int j = 0; j < 8; ++j) f[j] = bf2f(v[j]);
    float m = f[0];
    #pragma unroll
    for (int j = 1; j < 8; ++j) m = fmaxf(m, f[j]);
    #pragma unroll
    for (int o = 1; o < 64; o <<= 1) m = fmaxf(m, __shfl_xor(m, o, 64));
    __shared__ float smax[4], ssum[4];
    const int w = tid >> 6, lane = tid & 63;
    if (lane == 0) smax[w] = m;
    __syncthreads();
    m = fmaxf(fmaxf(smax[0], smax[1]), fmaxf(smax[2], smax[3]));
    float e[8], s = 0.f;
    #pragma unroll
    for (int j = 0; j < 8; ++j) { e[j] = expf(f[j] - m); s += e[j]; }
    #pragma unroll
    for (int o = 1; o < 64; o <<= 1) s += __shfl_xor(s, o, 64);
    if (lane == 0) ssum[w] = s;
    __syncthreads();
    s = ssum[0] + ssum[1] + ssum[2] + ssum[3];
    const float inv = 1.0f / s;
    u16x8 o8;
    #pragma unroll
    for (int j = 0; j < 8; ++j) o8[j] = f2bf(e[j] * inv);
    *(u16x8*)&prow[tid * 8] = o8;
}

// ---------------------------------------------------------------------------
extern "C" void kernel_launch(void* const* d_in, const int* in_sizes, int n_in,
                              void* d_out, int out_size, void* d_ws, size_t ws_size,
                              hipStream_t stream)
{
    const float* x  = (const float*)d_in[0];
    const float* Wq = (const float*)d_in[1];
    const float* bq = (const float*)d_in[2];
    const float* Wk = (const float*)d_in[3];
    const float* bk = (const float*)d_in[4];
    const float* Wv = (const float*)d_in[5];
    const float* bv = (const float*)d_in[6];
    const unsigned char* mraw = (const unsigned char*)d_in[7];

    const int BS = B_ * S_;                      // 16384
    unsigned short* Qb = (unsigned short*)d_ws;
    unsigned short* Kb = Qb + (size_t)BS * E_;
    unsigned short* VT = Kb + (size_t)BS * E_;
    unsigned short* Sc = VT + (size_t)BS * E_;
    unsigned short* xb = Sc;                                    // aliases Sc
    unsigned short* Wqb = Sc + (size_t)BS * E_;
    unsigned short* Wkb = Wqb + (size_t)E_ * E_;
    unsigned short* Wvb = Wkb + (size_t)E_ * E_;
    unsigned char* mcanon = (unsigned char*)(Sc + (size_t)B_ * S_ * S_);

    mask_canon_kernel<<<1, 256, 0, stream>>>(mraw, mcanon, BS);

    cvt_bf16_kernel<<<2048, 256, 0, stream>>>(x, xb, BS * E_ / 8);
    cvt_bf16_kernel<<<512, 256, 0, stream>>>(Wq, Wqb, E_ * E_ / 8);
    cvt_bf16_kernel<<<512, 256, 0, stream>>>(Wk, Wkb, E_ * E_ / 8);
    cvt_bf16_kernel<<<512, 256, 0, stream>>>(Wv, Wvb, E_ * E_ / 8);

    // Q = xb @ Wq^T + bq ; K = xb @ Wk^T + bk   (bf16 [BS][E])
    gemm256<2><<<dim3(E_ / 256, BS / 256), 512, 0, stream>>>(
        xb, Wqb, (void*)Qb, 0, 0, 0, E_, E_, E_, E_, nullptr, 0, 1.0f, bq);
    gemm256<2><<<dim3(E_ / 256, BS / 256), 512, 0, stream>>>(
        xb, Wkb, (void*)Kb, 0, 0, 0, E_, E_, E_, E_, nullptr, 0, 1.0f, bk);
    // VT[e][bs] = Wv[e,:] . x[bs,:] + bv[e]
    gemm256<3><<<dim3(BS / 256, E_ / 256), 512, 0, stream>>>(
        Wvb, xb, (void*)VT, 0, 0, 0, E_, E_, BS, E_, nullptr, 0, 1.0f, bv);

    // scores = (Q.K^T)/32, mask fill 1e-9, bf16
    gemm256<0><<<dim3(S_ / 256, S_ / 256, B_), 512, 0, stream>>>(
        Qb, Kb, (void*)Sc,
        (long long)S_ * E_, (long long)S_ * E_, (long long)S_ * S_,
        E_, E_, S_, E_, mcanon, S_, 0.03125f, nullptr);

    softmax_kernel<<<dim3(BS), 256, 0, stream>>>(Sc);

    // out = P . V (via V^T, NT)
    gemm256<1><<<dim3(E_ / 256, S_ / 256, B_), 512, 0, stream>>>(
        Sc, VT, d_out,
        (long long)S_ * S_, (long long)S_, (long long)S_ * E_,
        S_, BS, E_, S_, nullptr, 0, 1.0f, nullptr);
}

// Round 7
// 347.657 us; speedup vs baseline: 1.0488x; 1.0367x over previous
//
#include <hip/hip_runtime.h>
#include <hip/hip_bf16.h>

#define B_ 8
#define S_ 2048
#define E_ 1024

using f32x4 = __attribute__((ext_vector_type(4))) float;
using s16x8 = __attribute__((ext_vector_type(8))) short;
using u16x8 = __attribute__((ext_vector_type(8))) unsigned short;

typedef __attribute__((address_space(1))) unsigned int glb_u32;
typedef __attribute__((address_space(3))) unsigned int lds_u32;

#define FENCE() __builtin_amdgcn_sched_barrier(0)

static __device__ __forceinline__ unsigned short f2bf(float f) {
    union { float f; unsigned int u; } v; v.f = f;
    unsigned int u = v.u;
    u += 0x7FFFu + ((u >> 16) & 1u);   // round-to-nearest-even
    return (unsigned short)(u >> 16);
}
static __device__ __forceinline__ float bf2f(unsigned short h) {
    union { unsigned int u; float f; } v; v.u = ((unsigned int)h) << 16;
    return v.f;
}

// ---------------------------------------------------------------------------
// Mask canonicalizer: jax bool mask may arrive as uint8, int32 or float32.
// ---------------------------------------------------------------------------
__global__ __launch_bounds__(256) void mask_canon_kernel(
    const unsigned char* __restrict__ src, unsigned char* __restrict__ dst, int n)
{
    __shared__ int flags;
    if (threadIdx.x == 0) flags = 0;
    __syncthreads();
    int f = 0;
    for (int j = threadIdx.x; j < n; j += 256) {
        unsigned char b = src[j];
        if (b) {
            int p = j & 3;
            if (p == 1) f |= 1;
            if (p >= 2) f |= 2;
        }
    }
    if (f) atomicOr(&flags, f);
    __syncthreads();
    const int fl = flags;
    for (int i = threadIdx.x; i < n; i += 256) {
        unsigned char v;
        if (fl & 1)      v = (unsigned char)(src[i] != 0);
        else if (fl & 2) v = (unsigned char)(((const float*)(const void*)src)[i] != 0.0f);
        else             v = (unsigned char)(((const int*)(const void*)src)[i] != 0);
        dst[i] = v;
    }
}

// ---------------------------------------------------------------------------
// Fused fp32 -> bf16 convert of x, Wq, Wk, Wv in ONE launch.
// ---------------------------------------------------------------------------
__global__ __launch_bounds__(256) void cvt_all_kernel(
    const float* __restrict__ x,  unsigned short* __restrict__ xb,
    const float* __restrict__ w0, unsigned short* __restrict__ d0,
    const float* __restrict__ w1, unsigned short* __restrict__ d1,
    const float* __restrict__ w2, unsigned short* __restrict__ d2,
    int nx8, int nw8)
{
    const int total = nx8 + 3 * nw8;
    const int stride = gridDim.x * 256;
    for (int i = blockIdx.x * 256 + threadIdx.x; i < total; i += stride) {
        const float* s; unsigned short* d; int k;
        if (i < nx8)                { s = x;  d = xb; k = i; }
        else if (i < nx8 + nw8)     { s = w0; d = d0; k = i - nx8; }
        else if (i < nx8 + 2 * nw8) { s = w1; d = d1; k = i - nx8 - nw8; }
        else                        { s = w2; d = d2; k = i - nx8 - 2 * nw8; }
        float4 a = *(const float4*)(s + (size_t)k * 8);
        float4 b = *(const float4*)(s + (size_t)k * 8 + 4);
        u16x8 o;
        o[0]=f2bf(a.x); o[1]=f2bf(a.y); o[2]=f2bf(a.z); o[3]=f2bf(a.w);
        o[4]=f2bf(b.x); o[5]=f2bf(b.y); o[6]=f2bf(b.z); o[7]=f2bf(b.w);
        *(u16x8*)(d + (size_t)k * 8) = o;
    }
}

// ---------------------------------------------------------------------------
// 256x256 bf16 NT GEMM — software-pipelined K-loop, 2 barriers per K-tile.
//  - 8 waves (2M x 4N); BK=64; LDS 128KB double-buffered; st_16x32 swizzle
//    via pre-swizzled global SOURCE + swizzled read (0 bank conflicts, R4).
//  - Per iter: all 24 frag reads issued in pinned order (af03+bf01 first);
//    lgkmcnt(12) -> Q00 runs while the other 12 reads drain; lgkmcnt(0) ->
//    Q01; ONE barrier (reads of bo complete across waves -> overwrite-safe);
//    stage t+2 into bo under Q10+Q11; vmcnt(6); second barrier.
//  - vmcnt ledger (= R6, verified): retained 6 = this iter's t+2 issues
//    {B0,A0,A1}; B1(t+1) from iter front + t-1's tail drained -> at entry
//    barrier the next tile's buffer is fully staged.
// EPI: 0=QK(scale+mask->bf16) 1=PV(f32) 2=bias[ncol]->bf16 3=bias[mrow]->bf16
// ---------------------------------------------------------------------------
template<int EPI>
__global__ __launch_bounds__(512, 2) void gemm256(
    const unsigned short* __restrict__ A, const unsigned short* __restrict__ B,
    void* __restrict__ Cout,
    long long sAz, long long sBz, long long sCz,
    int lda, int ldb, int ldc, int K,
    const unsigned char* __restrict__ mask, int maskStride, float scale,
    const float* __restrict__ bias)
{
    __shared__ unsigned short lds[65536];   // 128 KB
    const int tid = threadIdx.x;
    const int lane = tid & 63, w = tid >> 6;
    const int wr = w >> 2, wc = w & 3;          // 2 x 4 waves
    const int fr = lane & 15, ch = lane >> 4;

    // T1: XCD-aware chunked swizzle of flattened block id (nwg % 8 == 0)
    const int gx = gridDim.x, gy = gridDim.y;
    const int nwg = gx * gy * gridDim.z;
    int bid = blockIdx.x + gx * (blockIdx.y + gy * blockIdx.z);
    bid = (bid & 7) * (nwg >> 3) + (bid >> 3);
    const int bx = bid % gx; int tmp = bid / gx;
    const int by = tmp % gy; const int bz = tmp / gy;

    const unsigned short* Ab = A + (size_t)bz * sAz;
    const unsigned short* Bb = B + (size_t)bz * sBz;
    const int m0 = by * 256, n0 = bx * 256;

    // swizzled frag-read lane offset (ushort units)
    const int rdlane = fr * 32 + ((ch * 8) ^ ((fr & 8) ? 16 : 0));
    // stage source mapping (inverse swizzle of the linear lane->phys write)
    const int local = (lane * 16) ^ (lane & 32);
    const int rloc = local >> 6;          // row within 16-row chunk
    const int cloc = (local >> 4) & 3;    // 16B col chunk

    f32x4 acc[8][4] = {};
    const int NT = K >> 6;

    auto STAGE = [&](const unsigned short* __restrict__ src, int ld, int base,
                     int ts, int half, int matoff, unsigned bo) {
        const int k0 = ts * 64;
        const int rowb = half * 128 + w * 16;
        #pragma unroll
        for (int kk = 0; kk < 2; ++kk) {
            const unsigned short* g = src + (size_t)(base + rowb + rloc) * ld
                                          + (k0 + kk * 32 + cloc * 8);
            __builtin_amdgcn_global_load_lds((const glb_u32*)g,
                (lds_u32*)&lds[bo + matoff + kk * 8192 + rowb * 32], 16, 0, 0);
        }
    };

    // prologue: tile0 fully + tile1 {A0,A1,B0}
    STAGE(Ab, lda, m0, 0, 0, 0, 0);      STAGE(Ab, lda, m0, 0, 1, 0, 0);
    STAGE(Bb, ldb, n0, 0, 0, 16384, 0);  STAGE(Bb, ldb, n0, 0, 1, 16384, 0);
    STAGE(Ab, lda, m0, 1, 0, 0, 32768);  STAGE(Ab, lda, m0, 1, 1, 0, 32768);
    STAGE(Bb, ldb, n0, 1, 0, 16384, 32768);
    asm volatile("s_waitcnt vmcnt(6)" ::: "memory");
    __builtin_amdgcn_s_barrier();

    for (int t = 0; t < NT; ++t) {
        const unsigned bo = (unsigned)(t & 1) * 32768u;
        const unsigned nbo = bo ^ 32768u;
        const int tp1 = (t + 1 < NT) ? t + 1 : NT - 1;
        const int tp2 = (t + 2 < NT) ? t + 2 : NT - 1;

        s16x8 af[8][2], bfv[4][2];
        // ---- reads, pinned order: group1 = af[0:4]+bf[0:2] (12) ----
        #pragma unroll
        for (int i = 0; i < 4; ++i)
            #pragma unroll
            for (int kk = 0; kk < 2; ++kk)
                af[i][kk] = *(const s16x8*)&lds[bo + kk * 8192 + (wr * 128 + i * 16) * 32 + rdlane];
        #pragma unroll
        for (int j = 0; j < 2; ++j)
            #pragma unroll
            for (int kk = 0; kk < 2; ++kk)
                bfv[j][kk] = *(const s16x8*)&lds[bo + 16384 + kk * 8192 + (wc * 64 + j * 16) * 32 + rdlane];
        FENCE();   // pin: group1 issues before group2
        // ---- group2 = af[4:8]+bf[2:4] (12) ----
        #pragma unroll
        for (int i = 4; i < 8; ++i)
            #pragma unroll
            for (int kk = 0; kk < 2; ++kk)
                af[i][kk] = *(const s16x8*)&lds[bo + kk * 8192 + (wr * 128 + i * 16) * 32 + rdlane];
        #pragma unroll
        for (int j = 2; j < 4; ++j)
            #pragma unroll
            for (int kk = 0; kk < 2; ++kk)
                bfv[j][kk] = *(const s16x8*)&lds[bo + 16384 + kk * 8192 + (wc * 64 + j * 16) * 32 + rdlane];
        STAGE(Bb, ldb, n0, tp1, 1, 16384, nbo);
        FENCE();
        asm volatile("s_waitcnt lgkmcnt(12)" ::: "memory");   // group1 ready
        FENCE();
        __builtin_amdgcn_s_setprio(1);
        #pragma unroll
        for (int i = 0; i < 4; ++i)       // Q00 — group2 drains underneath
            #pragma unroll
            for (int j = 0; j < 2; ++j)
                #pragma unroll
                for (int kk = 0; kk < 2; ++kk)
                    acc[i][j] = __builtin_amdgcn_mfma_f32_16x16x32_bf16(af[i][kk], bfv[j][kk], acc[i][j], 0, 0, 0);
        __builtin_amdgcn_s_setprio(0);
        FENCE();
        asm volatile("s_waitcnt lgkmcnt(0)" ::: "memory");    // all reads done
        FENCE();
        __builtin_amdgcn_s_setprio(1);
        #pragma unroll
        for (int i = 0; i < 4; ++i)       // Q01
            #pragma unroll
            for (int j = 0; j < 2; ++j)
                #pragma unroll
                for (int kk = 0; kk < 2; ++kk)
                    acc[i][2 + j] = __builtin_amdgcn_mfma_f32_16x16x32_bf16(af[i][kk], bfv[2 + j][kk], acc[i][2 + j], 0, 0, 0);
        __builtin_amdgcn_s_setprio(0);
        FENCE();
        __builtin_amdgcn_s_barrier();     // every wave's bo reads complete
        FENCE();
        // ---- stage t+2 into bo; Q10+Q11 hide the issue+flight ----
        STAGE(Bb, ldb, n0, tp2, 0, 16384, bo);
        STAGE(Ab, lda, m0, tp2, 0, 0, bo);
        STAGE(Ab, lda, m0, tp2, 1, 0, bo);
        FENCE();
        __builtin_amdgcn_s_setprio(1);
        #pragma unroll
        for (int i = 0; i < 4; ++i)       // Q10
            #pragma unroll
            for (int j = 0; j < 2; ++j)
                #pragma unroll
                for (int kk = 0; kk < 2; ++kk)
                    acc[4 + i][j] = __builtin_amdgcn_mfma_f32_16x16x32_bf16(af[4 + i][kk], bfv[j][kk], acc[4 + i][j], 0, 0, 0);
        #pragma unroll
        for (int i = 0; i < 4; ++i)       // Q11
            #pragma unroll
            for (int j = 0; j < 2; ++j)
                #pragma unroll
                for (int kk = 0; kk < 2; ++kk)
                    acc[4 + i][2 + j] = __builtin_amdgcn_mfma_f32_16x16x32_bf16(af[4 + i][kk], bfv[2 + j][kk], acc[4 + i][2 + j], 0, 0, 0);
        __builtin_amdgcn_s_setprio(0);
        FENCE();
        asm volatile("s_waitcnt vmcnt(6)" ::: "memory");      // retain t+2's 6
        FENCE();
        __builtin_amdgcn_s_barrier();     // next tile's buffer fully staged
    }

    // ---------------- epilogue ----------------
    if constexpr (EPI == 1) {
        float* Cb = (float*)Cout + (size_t)bz * sCz;
        #pragma unroll
        for (int j = 0; j < 4; ++j) {
            const int ncol = n0 + wc * 64 + j * 16 + fr;
            #pragma unroll
            for (int i = 0; i < 8; ++i)
                #pragma unroll
                for (int r = 0; r < 4; ++r) {
                    const int mrow = m0 + wr * 128 + i * 16 + ch * 4 + r;
                    Cb[(size_t)mrow * ldc + ncol] = acc[i][j][r];
                }
        }
    } else {
        unsigned short* Cb = (unsigned short*)Cout + (size_t)bz * sCz;
        const unsigned char* mb = (EPI == 0) ? mask + (size_t)bz * maskStride : nullptr;
        #pragma unroll
        for (int j = 0; j < 4; ++j) {
            const int ncol = n0 + wc * 64 + j * 16 + fr;
            bool msk = false; float bn = 0.f;
            if constexpr (EPI == 0) msk = mb[ncol] != 0;
            if constexpr (EPI == 2) bn = bias[ncol];
            #pragma unroll
            for (int i = 0; i < 8; ++i) {
                #pragma unroll
                for (int r = 0; r < 4; ++r) {
                    const int mrow = m0 + wr * 128 + i * 16 + ch * 4 + r;
                    float val;
                    if constexpr (EPI == 0)      val = msk ? 1e-9f : acc[i][j][r] * scale;
                    else if constexpr (EPI == 2) val = acc[i][j][r] + bn;
                    else                         val = acc[i][j][r] + bias[mrow];
                    Cb[(size_t)mrow * ldc + ncol] = f2bf(val);
                }
            }
        }
    }
}

// ---------------------------------------------------------------------------
// Row softmax over S_=2048 bf16 scores, in place.
// ---------------------------------------------------------------------------
__global__ __launch_bounds__(256) void softmax_kernel(unsigned short* __restrict__ P)
{
    const int row = blockIdx.x;
    const int tid = threadIdx.x;
    unsigned short* prow = P + (size_t)row * S_;
    u16x8 v = *(const u16x8*)&prow[tid * 8];
    float f[8];
    #pragma unroll
    for (int j = 0; j < 8; ++j) f[j] = bf2f(v[j]);
    float m = f[0];
    #pragma unroll
    for (int j = 1; j < 8; ++j) m = fmaxf(m, f[j]);
    #pragma unroll
    for (int o = 1; o < 64; o <<= 1) m = fmaxf(m, __shfl_xor(m, o, 64));
    __shared__ float smax[4], ssum[4];
    const int w = tid >> 6, lane = tid & 63;
    if (lane == 0) smax[w] = m;
    __syncthreads();
    m = fmaxf(fmaxf(smax[0], smax[1]), fmaxf(smax[2], smax[3]));
    float e[8], s = 0.f;
    #pragma unroll
    for (int j = 0; j < 8; ++j) { e[j] = expf(f[j] - m); s += e[j]; }
    #pragma unroll
    for (int o = 1; o < 64; o <<= 1) s += __shfl_xor(s, o, 64);
    if (lane == 0) ssum[w] = s;
    __syncthreads();
    s = ssum[0] + ssum[1] + ssum[2] + ssum[3];
    const float inv = 1.0f / s;
    u16x8 o8;
    #pragma unroll
    for (int j = 0; j < 8; ++j) o8[j] = f2bf(e[j] * inv);
    *(u16x8*)&prow[tid * 8] = o8;
}

// ---------------------------------------------------------------------------
extern "C" void kernel_launch(void* const* d_in, const int* in_sizes, int n_in,
                              void* d_out, int out_size, void* d_ws, size_t ws_size,
                              hipStream_t stream)
{
    const float* x  = (const float*)d_in[0];
    const float* Wq = (const float*)d_in[1];
    const float* bq = (const float*)d_in[2];
    const float* Wk = (const float*)d_in[3];
    const float* bk = (const float*)d_in[4];
    const float* Wv = (const float*)d_in[5];
    const float* bv = (const float*)d_in[6];
    const unsigned char* mraw = (const unsigned char*)d_in[7];

    const int BS = B_ * S_;                      // 16384
    unsigned short* Qb = (unsigned short*)d_ws;
    unsigned short* Kb = Qb + (size_t)BS * E_;
    unsigned short* VT = Kb + (size_t)BS * E_;
    unsigned short* Sc = VT + (size_t)BS * E_;
    unsigned short* xb = Sc;                                    // aliases Sc
    unsigned short* Wqb = Sc + (size_t)BS * E_;
    unsigned short* Wkb = Wqb + (size_t)E_ * E_;
    unsigned short* Wvb = Wkb + (size_t)E_ * E_;
    unsigned char* mcanon = (unsigned char*)(Sc + (size_t)B_ * S_ * S_);

    mask_canon_kernel<<<1, 256, 0, stream>>>(mraw, mcanon, BS);

    cvt_all_kernel<<<2048, 256, 0, stream>>>(
        x, xb, Wq, Wqb, Wk, Wkb, Wv, Wvb, BS * E_ / 8, E_ * E_ / 8);

    // Q = xb @ Wq^T + bq ; K = xb @ Wk^T + bk   (bf16 [BS][E])
    gemm256<2><<<dim3(E_ / 256, BS / 256), 512, 0, stream>>>(
        xb, Wqb, (void*)Qb, 0, 0, 0, E_, E_, E_, E_, nullptr, 0, 1.0f, bq);
    gemm256<2><<<dim3(E_ / 256, BS / 256), 512, 0, stream>>>(
        xb, Wkb, (void*)Kb, 0, 0, 0, E_, E_, E_, E_, nullptr, 0, 1.0f, bk);
    // VT[e][bs] = Wv[e,:] . x[bs,:] + bv[e]
    gemm256<3><<<dim3(BS / 256, E_ / 256), 512, 0, stream>>>(
        Wvb, xb, (void*)VT, 0, 0, 0, E_, E_, BS, E_, nullptr, 0, 1.0f, bv);

    // scores = (Q.K^T)/32, mask fill 1e-9, bf16
    gemm256<0><<<dim3(S_ / 256, S_ / 256, B_), 512, 0, stream>>>(
        Qb, Kb, (void*)Sc,
        (long long)S_ * E_, (long long)S_ * E_, (long long)S_ * S_,
        E_, E_, S_, E_, mcanon, S_, 0.03125f, nullptr);

    softmax_kernel<<<dim3(BS), 256, 0, stream>>>(Sc);

    // out = P . V (via V^T, NT)
    gemm256<1><<<dim3(E_ / 256, S_ / 256, B_), 512, 0, stream>>>(
        Sc, VT, d_out,
        (long long)S_ * S_, (long long)S_, (long long)S_ * E_,
        S_, BS, E_, S_, nullptr, 0, 1.0f, nullptr);
}

// Round 8
// 332.156 us; speedup vs baseline: 1.0977x; 1.0467x over previous
//
#include <hip/hip_runtime.h>
#include <hip/hip_bf16.h>

#define B_ 8
#define S_ 2048
#define E_ 1024

using f32x4 = __attribute__((ext_vector_type(4))) float;
using s16x8 = __attribute__((ext_vector_type(8))) short;
using u16x8 = __attribute__((ext_vector_type(8))) unsigned short;

typedef __attribute__((address_space(1))) unsigned int glb_u32;
typedef __attribute__((address_space(3))) unsigned int lds_u32;

#define FENCE() __builtin_amdgcn_sched_barrier(0)

static __device__ __forceinline__ unsigned short f2bf(float f) {
    union { float f; unsigned int u; } v; v.f = f;
    unsigned int u = v.u;
    u += 0x7FFFu + ((u >> 16) & 1u);   // round-to-nearest-even
    return (unsigned short)(u >> 16);
}
static __device__ __forceinline__ float bf2f(unsigned short h) {
    union { unsigned int u; float f; } v; v.u = ((unsigned int)h) << 16;
    return v.f;
}

// ---------------------------------------------------------------------------
// Mask canonicalizer: jax bool mask may arrive as uint8, int32 or float32.
// ---------------------------------------------------------------------------
__global__ __launch_bounds__(256) void mask_canon_kernel(
    const unsigned char* __restrict__ src, unsigned char* __restrict__ dst, int n)
{
    __shared__ int flags;
    if (threadIdx.x == 0) flags = 0;
    __syncthreads();
    int f = 0;
    for (int j = threadIdx.x; j < n; j += 256) {
        unsigned char b = src[j];
        if (b) {
            int p = j & 3;
            if (p == 1) f |= 1;
            if (p >= 2) f |= 2;
        }
    }
    if (f) atomicOr(&flags, f);
    __syncthreads();
    const int fl = flags;
    for (int i = threadIdx.x; i < n; i += 256) {
        unsigned char v;
        if (fl & 1)      v = (unsigned char)(src[i] != 0);
        else if (fl & 2) v = (unsigned char)(((const float*)(const void*)src)[i] != 0.0f);
        else             v = (unsigned char)(((const int*)(const void*)src)[i] != 0);
        dst[i] = v;
    }
}

// ---------------------------------------------------------------------------
// Fused fp32 -> bf16 convert of x, Wq, Wk, Wv in ONE launch.
// ---------------------------------------------------------------------------
__global__ __launch_bounds__(256) void cvt_all_kernel(
    const float* __restrict__ x,  unsigned short* __restrict__ xb,
    const float* __restrict__ w0, unsigned short* __restrict__ d0,
    const float* __restrict__ w1, unsigned short* __restrict__ d1,
    const float* __restrict__ w2, unsigned short* __restrict__ d2,
    int nx8, int nw8)
{
    const int total = nx8 + 3 * nw8;
    const int stride = gridDim.x * 256;
    for (int i = blockIdx.x * 256 + threadIdx.x; i < total; i += stride) {
        const float* s; unsigned short* d; int k;
        if (i < nx8)                { s = x;  d = xb; k = i; }
        else if (i < nx8 + nw8)     { s = w0; d = d0; k = i - nx8; }
        else if (i < nx8 + 2 * nw8) { s = w1; d = d1; k = i - nx8 - nw8; }
        else                        { s = w2; d = d2; k = i - nx8 - 2 * nw8; }
        float4 a = *(const float4*)(s + (size_t)k * 8);
        float4 b = *(const float4*)(s + (size_t)k * 8 + 4);
        u16x8 o;
        o[0]=f2bf(a.x); o[1]=f2bf(a.y); o[2]=f2bf(a.z); o[3]=f2bf(a.w);
        o[4]=f2bf(b.x); o[5]=f2bf(b.y); o[6]=f2bf(b.z); o[7]=f2bf(b.w);
        *(u16x8*)(d + (size_t)k * 8) = o;
    }
}

// ---------------------------------------------------------------------------
// 256x256 bf16 NT GEMM — R7 pipelined K-loop + R8 COALESCED EPILOGUE.
//  - K-loop unchanged from R7 (2 barriers/iter, counted lgkm/vmcnt, swizzled
//    LDS, 0 bank conflicts).
//  - Epilogue: R7 stores were 2B/4B scattered (32/64B segments) -> 2x HBM
//    write amplification (WRITE_SIZE 128MB vs 64MB ideal). Now: drain staging
//    (vmcnt0 - tail prefetches still land in LDS!), dump tile to LDS, barrier,
//    linear readback: 16B/lane, full 512B(bf16)/1KB(f32) row segments.
// EPI: 0=QK(scale+mask->bf16) 1=PV(f32) 2=bias[ncol]->bf16 3=bias[mrow]->bf16
// ---------------------------------------------------------------------------
template<int EPI>
__global__ __launch_bounds__(512, 2) void gemm256(
    const unsigned short* __restrict__ A, const unsigned short* __restrict__ B,
    void* __restrict__ Cout,
    long long sAz, long long sBz, long long sCz,
    int lda, int ldb, int ldc, int K,
    const unsigned char* __restrict__ mask, int maskStride, float scale,
    const float* __restrict__ bias)
{
    __shared__ unsigned short lds[65536];   // 128 KB
    const int tid = threadIdx.x;
    const int lane = tid & 63, w = tid >> 6;
    const int wr = w >> 2, wc = w & 3;          // 2 x 4 waves
    const int fr = lane & 15, ch = lane >> 4;

    // T1: XCD-aware chunked swizzle of flattened block id (nwg % 8 == 0)
    const int gx = gridDim.x, gy = gridDim.y;
    const int nwg = gx * gy * gridDim.z;
    int bid = blockIdx.x + gx * (blockIdx.y + gy * blockIdx.z);
    bid = (bid & 7) * (nwg >> 3) + (bid >> 3);
    const int bx = bid % gx; int tmp = bid / gx;
    const int by = tmp % gy; const int bz = tmp / gy;

    const unsigned short* Ab = A + (size_t)bz * sAz;
    const unsigned short* Bb = B + (size_t)bz * sBz;
    const int m0 = by * 256, n0 = bx * 256;

    // swizzled frag-read lane offset (ushort units)
    const int rdlane = fr * 32 + ((ch * 8) ^ ((fr & 8) ? 16 : 0));
    // stage source mapping (inverse swizzle of the linear lane->phys write)
    const int local = (lane * 16) ^ (lane & 32);
    const int rloc = local >> 6;          // row within 16-row chunk
    const int cloc = (local >> 4) & 3;    // 16B col chunk

    f32x4 acc[8][4] = {};
    const int NT = K >> 6;

    auto STAGE = [&](const unsigned short* __restrict__ src, int ld, int base,
                     int ts, int half, int matoff, unsigned bo) {
        const int k0 = ts * 64;
        const int rowb = half * 128 + w * 16;
        #pragma unroll
        for (int kk = 0; kk < 2; ++kk) {
            const unsigned short* g = src + (size_t)(base + rowb + rloc) * ld
                                          + (k0 + kk * 32 + cloc * 8);
            __builtin_amdgcn_global_load_lds((const glb_u32*)g,
                (lds_u32*)&lds[bo + matoff + kk * 8192 + rowb * 32], 16, 0, 0);
        }
    };

    // prologue: tile0 fully + tile1 {A0,A1,B0}
    STAGE(Ab, lda, m0, 0, 0, 0, 0);      STAGE(Ab, lda, m0, 0, 1, 0, 0);
    STAGE(Bb, ldb, n0, 0, 0, 16384, 0);  STAGE(Bb, ldb, n0, 0, 1, 16384, 0);
    STAGE(Ab, lda, m0, 1, 0, 0, 32768);  STAGE(Ab, lda, m0, 1, 1, 0, 32768);
    STAGE(Bb, ldb, n0, 1, 0, 16384, 32768);
    asm volatile("s_waitcnt vmcnt(6)" ::: "memory");
    __builtin_amdgcn_s_barrier();

    for (int t = 0; t < NT; ++t) {
        const unsigned bo = (unsigned)(t & 1) * 32768u;
        const unsigned nbo = bo ^ 32768u;
        const int tp1 = (t + 1 < NT) ? t + 1 : NT - 1;
        const int tp2 = (t + 2 < NT) ? t + 2 : NT - 1;

        s16x8 af[8][2], bfv[4][2];
        // ---- reads, pinned order: group1 = af[0:4]+bf[0:2] (12) ----
        #pragma unroll
        for (int i = 0; i < 4; ++i)
            #pragma unroll
            for (int kk = 0; kk < 2; ++kk)
                af[i][kk] = *(const s16x8*)&lds[bo + kk * 8192 + (wr * 128 + i * 16) * 32 + rdlane];
        #pragma unroll
        for (int j = 0; j < 2; ++j)
            #pragma unroll
            for (int kk = 0; kk < 2; ++kk)
                bfv[j][kk] = *(const s16x8*)&lds[bo + 16384 + kk * 8192 + (wc * 64 + j * 16) * 32 + rdlane];
        FENCE();   // pin: group1 issues before group2
        // ---- group2 = af[4:8]+bf[2:4] (12) ----
        #pragma unroll
        for (int i = 4; i < 8; ++i)
            #pragma unroll
            for (int kk = 0; kk < 2; ++kk)
                af[i][kk] = *(const s16x8*)&lds[bo + kk * 8192 + (wr * 128 + i * 16) * 32 + rdlane];
        #pragma unroll
        for (int j = 2; j < 4; ++j)
            #pragma unroll
            for (int kk = 0; kk < 2; ++kk)
                bfv[j][kk] = *(const s16x8*)&lds[bo + 16384 + kk * 8192 + (wc * 64 + j * 16) * 32 + rdlane];
        STAGE(Bb, ldb, n0, tp1, 1, 16384, nbo);
        FENCE();
        asm volatile("s_waitcnt lgkmcnt(12)" ::: "memory");   // group1 ready
        FENCE();
        __builtin_amdgcn_s_setprio(1);
        #pragma unroll
        for (int i = 0; i < 4; ++i)       // Q00 — group2 drains underneath
            #pragma unroll
            for (int j = 0; j < 2; ++j)
                #pragma unroll
                for (int kk = 0; kk < 2; ++kk)
                    acc[i][j] = __builtin_amdgcn_mfma_f32_16x16x32_bf16(af[i][kk], bfv[j][kk], acc[i][j], 0, 0, 0);
        __builtin_amdgcn_s_setprio(0);
        FENCE();
        asm volatile("s_waitcnt lgkmcnt(0)" ::: "memory");    // all reads done
        FENCE();
        __builtin_amdgcn_s_setprio(1);
        #pragma unroll
        for (int i = 0; i < 4; ++i)       // Q01
            #pragma unroll
            for (int j = 0; j < 2; ++j)
                #pragma unroll
                for (int kk = 0; kk < 2; ++kk)
                    acc[i][2 + j] = __builtin_amdgcn_mfma_f32_16x16x32_bf16(af[i][kk], bfv[2 + j][kk], acc[i][2 + j], 0, 0, 0);
        __builtin_amdgcn_s_setprio(0);
        FENCE();
        __builtin_amdgcn_s_barrier();     // every wave's bo reads complete
        FENCE();
        // ---- stage t+2 into bo; Q10+Q11 hide the issue+flight ----
        STAGE(Bb, ldb, n0, tp2, 0, 16384, bo);
        STAGE(Ab, lda, m0, tp2, 0, 0, bo);
        STAGE(Ab, lda, m0, tp2, 1, 0, bo);
        FENCE();
        __builtin_amdgcn_s_setprio(1);
        #pragma unroll
        for (int i = 0; i < 4; ++i)       // Q10
            #pragma unroll
            for (int j = 0; j < 2; ++j)
                #pragma unroll
                for (int kk = 0; kk < 2; ++kk)
                    acc[4 + i][j] = __builtin_amdgcn_mfma_f32_16x16x32_bf16(af[4 + i][kk], bfv[j][kk], acc[4 + i][j], 0, 0, 0);
        #pragma unroll
        for (int i = 0; i < 4; ++i)       // Q11
            #pragma unroll
            for (int j = 0; j < 2; ++j)
                #pragma unroll
                for (int kk = 0; kk < 2; ++kk)
                    acc[4 + i][2 + j] = __builtin_amdgcn_mfma_f32_16x16x32_bf16(af[4 + i][kk], bfv[2 + j][kk], acc[4 + i][2 + j], 0, 0, 0);
        __builtin_amdgcn_s_setprio(0);
        FENCE();
        asm volatile("s_waitcnt vmcnt(6)" ::: "memory");      // retain t+2's 6
        FENCE();
        __builtin_amdgcn_s_barrier();     // next tile's buffer fully staged
    }

    // ---------------- coalesced epilogue (via LDS transpose) ----------------
    // Drain: tail-iteration prefetches are still in flight INTO lds -> must
    // complete before we overwrite the buffer with C data.
    asm volatile("s_waitcnt vmcnt(0) lgkmcnt(0)" ::: "memory");
    __builtin_amdgcn_s_barrier();

    if constexpr (EPI == 1) {
        float* Cb = (float*)Cout + (size_t)bz * sCz;
        float* lf = (float*)lds;          // 128 rows x 256 f32 = 128 KB
        #pragma unroll
        for (int p = 0; p < 2; ++p) {
            if (p == 1) __syncthreads();  // protect reuse between passes
            #pragma unroll
            for (int j = 0; j < 4; ++j) {
                const int lcol = wc * 64 + j * 16 + fr;
                #pragma unroll
                for (int i = 0; i < 4; ++i)
                    #pragma unroll
                    for (int r = 0; r < 4; ++r) {
                        const int lrow = wr * 64 + i * 16 + ch * 4 + r;
                        lf[lrow * 256 + lcol] = acc[4 * p + i][j][r];
                    }
            }
            __syncthreads();
            // readback: 16 sweeps x 512 thr x 16B = 128KB; 1KB per row
            #pragma unroll
            for (int s = 0; s < 16; ++s) {
                const int lrow = s * 8 + (tid >> 6);
                const int colf = (tid & 63) * 4;
                float4 v = *(const float4*)&lf[lrow * 256 + colf];
                const int mrow = m0 + ((lrow >= 64) ? 128 : 0) + p * 64 + (lrow & 63);
                *(float4*)&Cb[(size_t)mrow * ldc + n0 + colf] = v;
            }
        }
    } else {
        unsigned short* Cb = (unsigned short*)Cout + (size_t)bz * sCz;
        const unsigned char* mb = (EPI == 0) ? mask + (size_t)bz * maskStride : nullptr;
        // full 256x256 bf16 tile = 128 KB, row-major [256][256] ushort
        #pragma unroll
        for (int j = 0; j < 4; ++j) {
            const int lcol = wc * 64 + j * 16 + fr;
            bool msk = false; float bn = 0.f;
            if constexpr (EPI == 0) msk = mb[n0 + lcol] != 0;
            if constexpr (EPI == 2) bn = bias[n0 + lcol];
            #pragma unroll
            for (int i = 0; i < 8; ++i) {
                #pragma unroll
                for (int r = 0; r < 4; ++r) {
                    const int lrow = wr * 128 + i * 16 + ch * 4 + r;
                    float val;
                    if constexpr (EPI == 0)      val = msk ? 1e-9f : acc[i][j][r] * scale;
                    else if constexpr (EPI == 2) val = acc[i][j][r] + bn;
                    else                         val = acc[i][j][r] + bias[m0 + lrow];
                    lds[lrow * 256 + lcol] = f2bf(val);
                }
            }
        }
        __syncthreads();
        // readback: 16 sweeps x 512 thr x 16B = 128KB; 512B per row
        #pragma unroll
        for (int s = 0; s < 16; ++s) {
            const int lrow = s * 16 + (tid >> 5);
            const int colu = (tid & 31) * 8;
            u16x8 v = *(const u16x8*)&lds[lrow * 256 + colu];
            *(u16x8*)&Cb[(size_t)(m0 + lrow) * ldc + n0 + colu] = v;
        }
    }
}

// ---------------------------------------------------------------------------
// Row softmax over S_=2048 bf16 scores, in place.
// ---------------------------------------------------------------------------
__global__ __launch_bounds__(256) void softmax_kernel(unsigned short* __restrict__ P)
{
    const int row = blockIdx.x;
    const int tid = threadIdx.x;
    unsigned short* prow = P + (size_t)row * S_;
    u16x8 v = *(const u16x8*)&prow[tid * 8];
    float f[8];
    #pragma unroll
    for (int j = 0; j < 8; ++j) f[j] = bf2f(v[j]);
    float m = f[0];
    #pragma unroll
    for (int j = 1; j < 8; ++j) m = fmaxf(m, f[j]);
    #pragma unroll
    for (int o = 1; o < 64; o <<= 1) m = fmaxf(m, __shfl_xor(m, o, 64));
    __shared__ float smax[4], ssum[4];
    const int w = tid >> 6, lane = tid & 63;
    if (lane == 0) smax[w] = m;
    __syncthreads();
    m = fmaxf(fmaxf(smax[0], smax[1]), fmaxf(smax[2], smax[3]));
    float e[8], s = 0.f;
    #pragma unroll
    for (int j = 0; j < 8; ++j) { e[j] = expf(f[j] - m); s += e[j]; }
    #pragma unroll
    for (int o = 1; o < 64; o <<= 1) s += __shfl_xor(s, o, 64);
    if (lane == 0) ssum[w] = s;
    __syncthreads();
    s = ssum[0] + ssum[1] + ssum[2] + ssum[3];
    const float inv = 1.0f / s;
    u16x8 o8;
    #pragma unroll
    for (int j = 0; j < 8; ++j) o8[j] = f2bf(e[j] * inv);
    *(u16x8*)&prow[tid * 8] = o8;
}

// ---------------------------------------------------------------------------
extern "C" void kernel_launch(void* const* d_in, const int* in_sizes, int n_in,
                              void* d_out, int out_size, void* d_ws, size_t ws_size,
                              hipStream_t stream)
{
    const float* x  = (const float*)d_in[0];
    const float* Wq = (const float*)d_in[1];
    const float* bq = (const float*)d_in[2];
    const float* Wk = (const float*)d_in[3];
    const float* bk = (const float*)d_in[4];
    const float* Wv = (const float*)d_in[5];
    const float* bv = (const float*)d_in[6];
    const unsigned char* mraw = (const unsigned char*)d_in[7];

    const int BS = B_ * S_;                      // 16384
    unsigned short* Qb = (unsigned short*)d_ws;
    unsigned short* Kb = Qb + (size_t)BS * E_;
    unsigned short* VT = Kb + (size_t)BS * E_;
    unsigned short* Sc = VT + (size_t)BS * E_;
    unsigned short* xb = Sc;                                    // aliases Sc
    unsigned short* Wqb = Sc + (size_t)BS * E_;
    unsigned short* Wkb = Wqb + (size_t)E_ * E_;
    unsigned short* Wvb = Wkb + (size_t)E_ * E_;
    unsigned char* mcanon = (unsigned char*)(Sc + (size_t)B_ * S_ * S_);

    mask_canon_kernel<<<1, 256, 0, stream>>>(mraw, mcanon, BS);

    cvt_all_kernel<<<2048, 256, 0, stream>>>(
        x, xb, Wq, Wqb, Wk, Wkb, Wv, Wvb, BS * E_ / 8, E_ * E_ / 8);

    // Q = xb @ Wq^T + bq ; K = xb @ Wk^T + bk   (bf16 [BS][E])
    gemm256<2><<<dim3(E_ / 256, BS / 256), 512, 0, stream>>>(
        xb, Wqb, (void*)Qb, 0, 0, 0, E_, E_, E_, E_, nullptr, 0, 1.0f, bq);
    gemm256<2><<<dim3(E_ / 256, BS / 256), 512, 0, stream>>>(
        xb, Wkb, (void*)Kb, 0, 0, 0, E_, E_, E_, E_, nullptr, 0, 1.0f, bk);
    // VT[e][bs] = Wv[e,:] . x[bs,:] + bv[e]
    gemm256<3><<<dim3(BS / 256, E_ / 256), 512, 0, stream>>>(
        Wvb, xb, (void*)VT, 0, 0, 0, E_, E_, BS, E_, nullptr, 0, 1.0f, bv);

    // scores = (Q.K^T)/32, mask fill 1e-9, bf16
    gemm256<0><<<dim3(S_ / 256, S_ / 256, B_), 512, 0, stream>>>(
        Qb, Kb, (void*)Sc,
        (long long)S_ * E_, (long long)S_ * E_, (long long)S_ * S_,
        E_, E_, S_, E_, mcanon, S_, 0.03125f, nullptr);

    softmax_kernel<<<dim3(BS), 256, 0, stream>>>(Sc);

    // out = P . V (via V^T, NT)
    gemm256<1><<<dim3(E_ / 256, S_ / 256, B_), 512, 0, stream>>>(
        Sc, VT, d_out,
        (long long)S_ * S_, (long long)S_, (long long)S_ * E_,
        S_, BS, E_, S_, nullptr, 0, 1.0f, nullptr);
}